// Round 14
// baseline (78.150 us; speedup 1.0000x reference)
//
#include <hip/hip_runtime.h>
#include <hip/hip_bf16.h>

#define T_TOK 4096
#define HID   150
#define HPAD  160
#define NSPAN 40915
#define MAXW  10
#define NT    10             // 160/16 col tiles

typedef __attribute__((ext_vector_type(8))) _Float16 f16x8;
typedef __attribute__((ext_vector_type(4))) float    f32x4;

static __device__ __forceinline__ f16x8 cvt8(const float* __restrict__ row, int kbase, int K) {
    f16x8 a;
    if (kbase + 8 <= K) {
        float4 v0 = *(const float4*)(row + kbase);
        float4 v1 = *(const float4*)(row + kbase + 4);
        a[0] = (_Float16)v0.x; a[1] = (_Float16)v0.y;
        a[2] = (_Float16)v0.z; a[3] = (_Float16)v0.w;
        a[4] = (_Float16)v1.x; a[5] = (_Float16)v1.y;
        a[6] = (_Float16)v1.z; a[7] = (_Float16)v1.w;
    } else {
#pragma unroll
        for (int e = 0; e < 8; e++)
            a[e] = (_Float16)((kbase + e < K) ? row[kbase + e] : 0.f);
    }
    return a;
}

// ---------------- k_prep: weight frag conversions + width constants (158 blocks)
__global__ __launch_bounds__(256) void k_prep(
    const float* __restrict__ aW1, const float* __restrict__ sW1,
    const float* __restrict__ aW2, const float* __restrict__ sW2,
    const float* __restrict__ wt, const float* __restrict__ sb1,
    _Float16* __restrict__ fW1, _Float16* __restrict__ fA1,
    _Float16* __restrict__ fB1, _Float16* __restrict__ fE1,
    _Float16* __restrict__ fA2, _Float16* __restrict__ fW2,
    float* __restrict__ wc)
{
    const int b = blockIdx.x;
    const int w = threadIdx.x >> 6, l = threadIdx.x & 63;

    if (b < 148) {
        int tw = b * 4 + w;
        if (tw >= 590) return;
        const float* src; int srcK, off; _Float16* d;
        if      (tw < 130) { src = aW1;             srcK = 400; off = 0;   d = fW1; }
        else if (tw < 260) { src = sW1;             srcK = 400; off = 130; d = fA1; }
        else if (tw < 390) { src = sW1 + 400 * HID; srcK = 400; off = 260; d = fB1; }
        else if (tw < 490) { src = sW1 + 800 * HID; srcK = 300; off = 390; d = fE1; }
        else if (tw < 540) { src = aW2;             srcK = 150; off = 490; d = fA2; }
        else               { src = sW2;             srcK = 150; off = 540; d = fW2; }
        int tb = tw - off;
        int kt = tb / NT, nt = tb - kt * NT;
        int n = nt * 16 + (l & 15);
        int kbase = kt * 32 + (l >> 4) * 8;
        f16x8 hv;
#pragma unroll
        for (int e = 0; e < 8; e++) {
            int k = kbase + e;
            float f = (k < srcK && n < HID) ? src[(size_t)k * HID + n] : 0.f;
            hv[e] = (_Float16)f;
        }
        *(f16x8*)(d + ((size_t)tb * 64 + l) * 8) = hv;
    } else {
        int n = b - 147;             // 1..10
        int c = threadIdx.x;
        if (c >= HPAD) return;
        float s = 0.f;
        if (c < HID) {
            const int dt[11] = {0, 1, 2, 3, 4, 4, 4, 4, 5, 5, 5};
            const float* ww = wt + dt[n] * 20;
            s = sb1[c];
#pragma unroll
            for (int j = 0; j < 20; j++) s = fmaf(ww[j], sW1[(1100 + j) * HID + c], s);
        }
        wc[(n - 1) * HPAD + c] = s;
    }
}

// ---------------- k_proj: grid (128, 4) x 512 threads (8 waves), split-K (R11 config).
__global__ __launch_bounds__(512) void k_proj(
    const float* __restrict__ states, const float* __restrict__ embeds,
    const _Float16* __restrict__ fW1, const _Float16* __restrict__ fA1,
    const _Float16* __restrict__ fB1, const _Float16* __restrict__ fE1,
    const _Float16* __restrict__ fA2,
    const float* __restrict__ ab1, const float* __restrict__ ab2,
    const float* __restrict__ aW3, const float* __restrict__ ab3,
    _Float16* __restrict__ Abuf, _Float16* __restrict__ Bbuf,
    _Float16* __restrict__ Ebuf, float* __restrict__ scores)
{
    __shared__ float smP[256 * 21];
    __shared__ alignas(16) _Float16 hh[5120];
    __shared__ float red[4][16];

    const float* Asrc; int lda, srcK, KT; const _Float16* Bf; _Float16* C = nullptr;
    switch (blockIdx.y) {
        case 0: Asrc = states; lda = 400; srcK = 400; KT = 13; Bf = fW1; break;
        case 1: Asrc = states; lda = 400; srcK = 400; KT = 13; Bf = fA1; C = Abuf; break;
        case 2: Asrc = states; lda = 400; srcK = 400; KT = 13; Bf = fB1; C = Bbuf; break;
        default:Asrc = embeds; lda = 300; srcK = 300; KT = 10; Bf = fE1; C = Ebuf; break;
    }
    const int tid = threadIdx.x;
    const int w   = tid >> 6, l = tid & 63;
    const int mtl = w >> 2;
    const int nh  = (w >> 1) & 1;
    const int kh  = w & 1;
    const int mt  = blockIdx.x * 2 + mtl;
    const int m15 = l & 15;
    const int koff = (l >> 4) * 8;
    const float* arow = Asrc + (size_t)(mt * 16 + m15) * lda;
    const f16x8* pB = (const f16x8*)Bf;
    const int pid = (mtl * 2 + nh) * 64 + l;

    f32x4 acc[5];
#pragma unroll
    for (int c = 0; c < 5; c++) acc[c] = (f32x4){0.f, 0.f, 0.f, 0.f};

    if (KT == 13) {
        if (kh == 0) {
#pragma unroll
            for (int kt = 0; kt < 7; ++kt) {
                f16x8 a = cvt8(arow, kt * 32 + koff, 400);
#pragma unroll
                for (int c = 0; c < 5; c++) {
                    f16x8 bv = pB[(size_t)(kt * NT + nh * 5 + c) * 64 + l];
                    acc[c] = __builtin_amdgcn_mfma_f32_16x16x32_f16(a, bv, acc[c], 0, 0, 0);
                }
            }
        } else {
#pragma unroll
            for (int kt = 7; kt < 13; ++kt) {
                f16x8 a = cvt8(arow, kt * 32 + koff, 400);
#pragma unroll
                for (int c = 0; c < 5; c++) {
                    f16x8 bv = pB[(size_t)(kt * NT + nh * 5 + c) * 64 + l];
                    acc[c] = __builtin_amdgcn_mfma_f32_16x16x32_f16(a, bv, acc[c], 0, 0, 0);
                }
            }
        }
    } else {
        if (kh == 0) {
#pragma unroll
            for (int kt = 0; kt < 5; ++kt) {
                f16x8 a = cvt8(arow, kt * 32 + koff, 300);
#pragma unroll
                for (int c = 0; c < 5; c++) {
                    f16x8 bv = pB[(size_t)(kt * NT + nh * 5 + c) * 64 + l];
                    acc[c] = __builtin_amdgcn_mfma_f32_16x16x32_f16(a, bv, acc[c], 0, 0, 0);
                }
            }
        } else {
#pragma unroll
            for (int kt = 5; kt < 10; ++kt) {
                f16x8 a = cvt8(arow, kt * 32 + koff, 300);
#pragma unroll
                for (int c = 0; c < 5; c++) {
                    f16x8 bv = pB[(size_t)(kt * NT + nh * 5 + c) * 64 + l];
                    acc[c] = __builtin_amdgcn_mfma_f32_16x16x32_f16(a, bv, acc[c], 0, 0, 0);
                }
            }
        }
    }

    if (kh == 1) {
#pragma unroll
        for (int c = 0; c < 5; c++)
#pragma unroll
            for (int r = 0; r < 4; r++) smP[pid * 21 + c * 4 + r] = acc[c][r];
    }
    __syncthreads();
    if (kh == 0) {
#pragma unroll
        for (int c = 0; c < 5; c++)
#pragma unroll
            for (int r = 0; r < 4; r++) acc[c][r] += smP[pid * 21 + c * 4 + r];
    }

    if (blockIdx.y != 0) {
        if (kh == 0) {
            const int m0 = mt * 16;
#pragma unroll
            for (int c = 0; c < 5; c++) {
                int col = (nh * 5 + c) * 16 + m15;
#pragma unroll
                for (int r = 0; r < 4; r++) {
                    int row = m0 + (l >> 4) * 4 + r;
                    C[(size_t)row * HPAD + col] = (_Float16)acc[c][r];
                }
            }
        }
        return;
    }

    if (kh == 0) {
#pragma unroll
        for (int c = 0; c < 5; c++) {
            int u   = nh * 5 + c;
            int col = u * 16 + m15;
            float bb = (col < HID) ? ab1[col] : 0.f;
            int kt2 = u >> 1;
            int g  = (u & 1) * 2 + (m15 >> 3);
            int e  = m15 & 7;
#pragma unroll
            for (int r = 0; r < 4; r++) {
                int rloc = (l >> 4) * 4 + r;
                float v = fmaxf(acc[c][r] + bb, 0.f);
                hh[((mtl * 5 + kt2) * 64 + g * 16 + rloc) * 8 + e] = (_Float16)v;
            }
        }
    }
    __syncthreads();

    if (kh == 0) {
        const f16x8* pH = (const f16x8*)hh;
        const f16x8* pB2 = (const f16x8*)fA2;
        f32x4 acc2[5];
#pragma unroll
        for (int c = 0; c < 5; c++) acc2[c] = (f32x4){0.f, 0.f, 0.f, 0.f};
#pragma unroll
        for (int kt = 0; kt < 5; ++kt) {
            f16x8 a = pH[(mtl * 5 + kt) * 64 + l];
#pragma unroll
            for (int c = 0; c < 5; c++) {
                f16x8 bv = pB2[(size_t)(kt * NT + nh * 5 + c) * 64 + l];
                acc2[c] = __builtin_amdgcn_mfma_f32_16x16x32_f16(a, bv, acc2[c], 0, 0, 0);
            }
        }
        float p[4] = {0.f, 0.f, 0.f, 0.f};
#pragma unroll
        for (int c = 0; c < 5; c++) {
            int col = (nh * 5 + c) * 16 + m15;
            float bb = (col < HID) ? ab2[col] : 0.f;
            float wv = (col < HID) ? aW3[col] : 0.f;
#pragma unroll
            for (int r = 0; r < 4; r++) {
                float v = fmaxf(acc2[c][r] + bb, 0.f);
                p[r] = fmaf(v, wv, p[r]);
            }
        }
#pragma unroll
        for (int off = 1; off < 16; off <<= 1)
#pragma unroll
            for (int r = 0; r < 4; r++) p[r] += __shfl_xor(p[r], off);
        if (m15 == 0)
#pragma unroll
            for (int r = 0; r < 4; r++) red[mtl * 2 + nh][(l >> 4) * 4 + r] = p[r];
    }
    __syncthreads();
    if (tid < 32) {
        scores[blockIdx.x * 32 + tid] =
            red[(tid >> 4) * 2 + 0][tid & 15] + red[(tid >> 4) * 2 + 1][tid & 15] + ab3[0];
    }
}

// ---------------- k_spanfinal: 1279 blocks x 32 spans (R11 config, no staging).
__global__ __launch_bounds__(256) void k_spanfinal(
    const float* __restrict__ scores, const _Float16* __restrict__ Abuf,
    const _Float16* __restrict__ Bbuf, const _Float16* __restrict__ Ebuf,
    const float* __restrict__ wc,
    const _Float16* __restrict__ fW2,
    const float* __restrict__ sb2, const float* __restrict__ sW3,
    const float* __restrict__ sb3, float* __restrict__ out)
{
    __shared__ alignas(16) _Float16 hh[5120];
    __shared__ float wg[32][10];
    __shared__ int   stI[32], nnI[32];
    __shared__ float red[4][16];

    const int tid = threadIdx.x;
    const int s0  = blockIdx.x * 32;

    // phase 0: softmax, 8 lanes per span
    {
        int sl = tid >> 3, k = tid & 7;
        int span = s0 + sl;
        int n = 1, start = 0;
        if (span < NSPAN) {
            int base = 0;
#pragma unroll
            for (int i = 1; i <= MAXW; i++) {
                int ww = T_TOK - i + 1;
                if (span < base + ww) { n = i; break; }
                base += ww;
            }
            start = span - base;
        }
        float x0 = (k < n)     ? scores[start + k]     : -1e30f;
        float x1 = (k + 8 < n) ? scores[start + k + 8] : -1e30f;
        float m = fmaxf(x0, x1);
        m = fmaxf(m, __shfl_xor(m, 1));
        m = fmaxf(m, __shfl_xor(m, 2));
        m = fmaxf(m, __shfl_xor(m, 4));
        float e0 = __expf(x0 - m), e1 = __expf(x1 - m);
        float s = e0 + e1;
        s += __shfl_xor(s, 1);
        s += __shfl_xor(s, 2);
        s += __shfl_xor(s, 4);
        float inv = 1.f / s;
        wg[sl][k] = e0 * inv;
        if (k < 2) wg[sl][k + 8] = e1 * inv;
        if (k == 0) { stI[sl] = start; nnI[sl] = n; }
    }
    __syncthreads();

    // phase 1: 640 tasks
#pragma unroll
    for (int it = 0; it < 3; ++it) {
        int task = it * 256 + tid;
        if (task < 640) {
            int sl = task / 20;
            int q  = task - sl * 20;
            int start = stI[sl];
            int nn = nnI[sl];
            int d0 = q * 8;
            f16x8 a8 = *(const f16x8*)(Abuf + (size_t)start * HPAD + d0);
            f16x8 b8 = *(const f16x8*)(Bbuf + (size_t)(start + nn - 1) * HPAD + d0);
            const float* wr = wc + (nn - 1) * HPAD + d0;
            float v[8];
#pragma unroll
            for (int e = 0; e < 8; e++) v[e] = (float)a8[e] + (float)b8[e] + wr[e];
#pragma unroll
            for (int i = 0; i < MAXW; i++) {
                int ridx = min(start + i, T_TOK - 1);
                f16x8 e8 = *(const f16x8*)(Ebuf + (size_t)ridx * HPAD + d0);
                float aa = wg[sl][i];
#pragma unroll
                for (int e = 0; e < 8; e++) v[e] = fmaf(aa, (float)e8[e], v[e]);
            }
            f16x8 hv;
#pragma unroll
            for (int e = 0; e < 8; e++) hv[e] = (_Float16)fmaxf(v[e], 0.f);
            int mtl = sl >> 4, smr = sl & 15;
            int kt = q >> 2, gg = q & 3;
            *(f16x8*)(hh + ((mtl * 5 + kt) * 64 + gg * 16 + smr) * 8) = hv;
        }
    }
    __syncthreads();

    // phase 2: GEMM (K=160) vs fW2 + relu + dot(sW3) -> out
    const int w = tid >> 6, l = tid & 63;
    const int mtl = w >> 1, nh = w & 1;
    const int m15 = l & 15;
    const f16x8* pH = (const f16x8*)hh;
    const f16x8* pB = (const f16x8*)fW2;
    f32x4 acc[5];
#pragma unroll
    for (int c = 0; c < 5; c++) acc[c] = (f32x4){0.f, 0.f, 0.f, 0.f};
#pragma unroll
    for (int kt = 0; kt < 5; ++kt) {
        f16x8 a = pH[(mtl * 5 + kt) * 64 + l];
#pragma unroll
        for (int c = 0; c < 5; c++) {
            f16x8 bv = pB[(size_t)(kt * NT + nh * 5 + c) * 64 + l];
            acc[c] = __builtin_amdgcn_mfma_f32_16x16x32_f16(a, bv, acc[c], 0, 0, 0);
        }
    }
    float p[4] = {0.f, 0.f, 0.f, 0.f};
#pragma unroll
    for (int c = 0; c < 5; c++) {
        int col = (nh * 5 + c) * 16 + m15;
        float bb = (col < HID) ? sb2[col] : 0.f;
        float wv = (col < HID) ? sW3[col] : 0.f;
#pragma unroll
        for (int r = 0; r < 4; r++) {
            float v = fmaxf(acc[c][r] + bb, 0.f);
            p[r] = fmaf(v, wv, p[r]);
        }
    }
#pragma unroll
    for (int off = 1; off < 16; off <<= 1)
#pragma unroll
        for (int r = 0; r < 4; r++) p[r] += __shfl_xor(p[r], off);
    if (m15 == 0)
#pragma unroll
        for (int r = 0; r < 4; r++) red[w][(l >> 4) * 4 + r] = p[r];
    __syncthreads();
    if (tid < 32) {
        int row = s0 + tid;
        if (row < NSPAN)
            out[row] = red[(tid >> 4) * 2 + 0][tid & 15] +
                       red[(tid >> 4) * 2 + 1][tid & 15] + sb3[0];
    }
}

extern "C" void kernel_launch(void* const* d_in, const int* in_sizes, int n_in,
                              void* d_out, int out_size, void* d_ws, size_t ws_size,
                              hipStream_t stream) {
    const float* embeds = (const float*)d_in[0];
    const float* states = (const float*)d_in[1];
    const float* aW1 = (const float*)d_in[2];
    const float* ab1 = (const float*)d_in[3];
    const float* aW2 = (const float*)d_in[4];
    const float* ab2 = (const float*)d_in[5];
    const float* aW3 = (const float*)d_in[6];
    const float* ab3 = (const float*)d_in[7];
    const float* wt  = (const float*)d_in[8];
    const float* sW1 = (const float*)d_in[9];
    const float* sb1 = (const float*)d_in[10];
    const float* sW2 = (const float*)d_in[11];
    const float* sb2 = (const float*)d_in[12];
    const float* sW3 = (const float*)d_in[13];
    const float* sb3 = (const float*)d_in[14];
    float* out = (float*)d_out;

    char* W = (char*)d_ws;
    _Float16* Abuf = (_Float16*)(W + 0);          // 4096*160*2 = 1310720
    _Float16* Bbuf = (_Float16*)(W + 1310720);
    _Float16* Ebuf = (_Float16*)(W + 2621440);
    float* scores  = (float*)(W + 3932160);       // 16384
    float* wcbuf   = (float*)(W + 3948544);       // 6400
    _Float16* fW1  = (_Float16*)(W + 3954944);    // 416*160*2 = 133120
    _Float16* fA1  = (_Float16*)(W + 4088064);
    _Float16* fB1  = (_Float16*)(W + 4221184);
    _Float16* fE1  = (_Float16*)(W + 4354304);    // 320*160*2 = 102400
    _Float16* fA2  = (_Float16*)(W + 4456704);    // 160*160*2 = 51200
    _Float16* fW2  = (_Float16*)(W + 4507904);
    // probe scratch (k_proj duplicate outputs)
    _Float16* Abuf2 = (_Float16*)(W + 4560896);
    _Float16* Bbuf2 = (_Float16*)(W + 5871616);
    _Float16* Ebuf2 = (_Float16*)(W + 7182336);
    float* scores2  = (float*)(W + 8493056);

    // weight frags + width constants (158 blocks)
    k_prep<<<158, 256, 0, stream>>>(aW1, sW1, aW2, sW2, wt, sb1,
                                    fW1, fA1, fB1, fE1, fA2, fW2, wcbuf);
    // projections + fused attention -> scores (512 blocks x 8 waves, split-K)
    k_proj<<<dim3(128, 4), 512, 0, stream>>>(states, embeds,
        fW1, fA1, fB1, fE1, fA2, ab1, ab2, aW3, ab3, Abuf, Bbuf, Ebuf, scores);
    // spans + final MLP -> out (1279 blocks)
    k_spanfinal<<<1279, 256, 0, stream>>>(scores, Abuf, Bbuf, Ebuf, wcbuf,
        fW2, sb2, sW3, sb3, out);
    // ---- decomposition probe: 4 idempotent k_proj duplicates into scratch.
    // dur - 37.6 ≈ 4*(t_proj + oh). Removed next round.
    k_proj<<<dim3(128, 4), 512, 0, stream>>>(states, embeds,
        fW1, fA1, fB1, fE1, fA2, ab1, ab2, aW3, ab3, Abuf2, Bbuf2, Ebuf2, scores2);
    k_proj<<<dim3(128, 4), 512, 0, stream>>>(states, embeds,
        fW1, fA1, fB1, fE1, fA2, ab1, ab2, aW3, ab3, Abuf2, Bbuf2, Ebuf2, scores2);
    k_proj<<<dim3(128, 4), 512, 0, stream>>>(states, embeds,
        fW1, fA1, fB1, fE1, fA2, ab1, ab2, aW3, ab3, Abuf2, Bbuf2, Ebuf2, scores2);
    k_proj<<<dim3(128, 4), 512, 0, stream>>>(states, embeds,
        fW1, fA1, fB1, fE1, fA2, ab1, ab2, aW3, ab3, Abuf2, Bbuf2, Ebuf2, scores2);
}

// Round 15
// 39.044 us; speedup vs baseline: 2.0016x; 2.0016x over previous
//
#include <hip/hip_runtime.h>
#include <hip/hip_bf16.h>

#define T_TOK 4096
#define HID   150
#define HPAD  160
#define NSPAN 40915
#define MAXW  10
#define NT    10             // 160/16 col tiles

typedef __attribute__((ext_vector_type(8))) _Float16 f16x8;
typedef __attribute__((ext_vector_type(4))) float    f32x4;

static __device__ __forceinline__ f16x8 cvt8(const float* __restrict__ row, int kbase, int K) {
    f16x8 a;
    if (kbase + 8 <= K) {
        float4 v0 = *(const float4*)(row + kbase);
        float4 v1 = *(const float4*)(row + kbase + 4);
        a[0] = (_Float16)v0.x; a[1] = (_Float16)v0.y;
        a[2] = (_Float16)v0.z; a[3] = (_Float16)v0.w;
        a[4] = (_Float16)v1.x; a[5] = (_Float16)v1.y;
        a[6] = (_Float16)v1.z; a[7] = (_Float16)v1.w;
    } else {
#pragma unroll
        for (int e = 0; e < 8; e++)
            a[e] = (_Float16)((kbase + e < K) ? row[kbase + e] : 0.f);
    }
    return a;
}

// ---------------- k_prep: weight frag conversions + width constants (158 blocks)
__global__ __launch_bounds__(256) void k_prep(
    const float* __restrict__ aW1, const float* __restrict__ sW1,
    const float* __restrict__ aW2, const float* __restrict__ sW2,
    const float* __restrict__ wt, const float* __restrict__ sb1,
    _Float16* __restrict__ fW1, _Float16* __restrict__ fA1,
    _Float16* __restrict__ fB1, _Float16* __restrict__ fE1,
    _Float16* __restrict__ fA2, _Float16* __restrict__ fW2,
    float* __restrict__ wc)
{
    const int b = blockIdx.x;
    const int w = threadIdx.x >> 6, l = threadIdx.x & 63;

    if (b < 148) {
        int tw = b * 4 + w;
        if (tw >= 590) return;
        const float* src; int srcK, off; _Float16* d;
        if      (tw < 130) { src = aW1;             srcK = 400; off = 0;   d = fW1; }
        else if (tw < 260) { src = sW1;             srcK = 400; off = 130; d = fA1; }
        else if (tw < 390) { src = sW1 + 400 * HID; srcK = 400; off = 260; d = fB1; }
        else if (tw < 490) { src = sW1 + 800 * HID; srcK = 300; off = 390; d = fE1; }
        else if (tw < 540) { src = aW2;             srcK = 150; off = 490; d = fA2; }
        else               { src = sW2;             srcK = 150; off = 540; d = fW2; }
        int tb = tw - off;
        int kt = tb / NT, nt = tb - kt * NT;
        int n = nt * 16 + (l & 15);
        int kbase = kt * 32 + (l >> 4) * 8;
        f16x8 hv;
#pragma unroll
        for (int e = 0; e < 8; e++) {
            int k = kbase + e;
            float f = (k < srcK && n < HID) ? src[(size_t)k * HID + n] : 0.f;
            hv[e] = (_Float16)f;
        }
        *(f16x8*)(d + ((size_t)tb * 64 + l) * 8) = hv;
    } else {
        int n = b - 147;             // 1..10
        int c = threadIdx.x;
        if (c >= HPAD) return;
        float s = 0.f;
        if (c < HID) {
            const int dt[11] = {0, 1, 2, 3, 4, 4, 4, 4, 5, 5, 5};
            const float* ww = wt + dt[n] * 20;
            s = sb1[c];
#pragma unroll
            for (int j = 0; j < 20; j++) s = fmaf(ww[j], sW1[(1100 + j) * HID + c], s);
        }
        wc[(n - 1) * HPAD + c] = s;
    }
}

// ---------------- k_proj: grid (128, 4) x 512 threads (8 waves), split-K (R11 config).
__global__ __launch_bounds__(512) void k_proj(
    const float* __restrict__ states, const float* __restrict__ embeds,
    const _Float16* __restrict__ fW1, const _Float16* __restrict__ fA1,
    const _Float16* __restrict__ fB1, const _Float16* __restrict__ fE1,
    const _Float16* __restrict__ fA2,
    const float* __restrict__ ab1, const float* __restrict__ ab2,
    const float* __restrict__ aW3, const float* __restrict__ ab3,
    _Float16* __restrict__ Abuf, _Float16* __restrict__ Bbuf,
    _Float16* __restrict__ Ebuf, float* __restrict__ scores)
{
    __shared__ float smP[256 * 21];
    __shared__ alignas(16) _Float16 hh[5120];
    __shared__ float red[4][16];

    const float* Asrc; int lda, srcK, KT; const _Float16* Bf; _Float16* C = nullptr;
    switch (blockIdx.y) {
        case 0: Asrc = states; lda = 400; srcK = 400; KT = 13; Bf = fW1; break;
        case 1: Asrc = states; lda = 400; srcK = 400; KT = 13; Bf = fA1; C = Abuf; break;
        case 2: Asrc = states; lda = 400; srcK = 400; KT = 13; Bf = fB1; C = Bbuf; break;
        default:Asrc = embeds; lda = 300; srcK = 300; KT = 10; Bf = fE1; C = Ebuf; break;
    }
    const int tid = threadIdx.x;
    const int w   = tid >> 6, l = tid & 63;
    const int mtl = w >> 2;
    const int nh  = (w >> 1) & 1;
    const int kh  = w & 1;
    const int mt  = blockIdx.x * 2 + mtl;
    const int m15 = l & 15;
    const int koff = (l >> 4) * 8;
    const float* arow = Asrc + (size_t)(mt * 16 + m15) * lda;
    const f16x8* pB = (const f16x8*)Bf;
    const int pid = (mtl * 2 + nh) * 64 + l;

    f32x4 acc[5];
#pragma unroll
    for (int c = 0; c < 5; c++) acc[c] = (f32x4){0.f, 0.f, 0.f, 0.f};

    if (KT == 13) {
        if (kh == 0) {
#pragma unroll
            for (int kt = 0; kt < 7; ++kt) {
                f16x8 a = cvt8(arow, kt * 32 + koff, 400);
#pragma unroll
                for (int c = 0; c < 5; c++) {
                    f16x8 bv = pB[(size_t)(kt * NT + nh * 5 + c) * 64 + l];
                    acc[c] = __builtin_amdgcn_mfma_f32_16x16x32_f16(a, bv, acc[c], 0, 0, 0);
                }
            }
        } else {
#pragma unroll
            for (int kt = 7; kt < 13; ++kt) {
                f16x8 a = cvt8(arow, kt * 32 + koff, 400);
#pragma unroll
                for (int c = 0; c < 5; c++) {
                    f16x8 bv = pB[(size_t)(kt * NT + nh * 5 + c) * 64 + l];
                    acc[c] = __builtin_amdgcn_mfma_f32_16x16x32_f16(a, bv, acc[c], 0, 0, 0);
                }
            }
        }
    } else {
        if (kh == 0) {
#pragma unroll
            for (int kt = 0; kt < 5; ++kt) {
                f16x8 a = cvt8(arow, kt * 32 + koff, 300);
#pragma unroll
                for (int c = 0; c < 5; c++) {
                    f16x8 bv = pB[(size_t)(kt * NT + nh * 5 + c) * 64 + l];
                    acc[c] = __builtin_amdgcn_mfma_f32_16x16x32_f16(a, bv, acc[c], 0, 0, 0);
                }
            }
        } else {
#pragma unroll
            for (int kt = 5; kt < 10; ++kt) {
                f16x8 a = cvt8(arow, kt * 32 + koff, 300);
#pragma unroll
                for (int c = 0; c < 5; c++) {
                    f16x8 bv = pB[(size_t)(kt * NT + nh * 5 + c) * 64 + l];
                    acc[c] = __builtin_amdgcn_mfma_f32_16x16x32_f16(a, bv, acc[c], 0, 0, 0);
                }
            }
        }
    }

    if (kh == 1) {
#pragma unroll
        for (int c = 0; c < 5; c++)
#pragma unroll
            for (int r = 0; r < 4; r++) smP[pid * 21 + c * 4 + r] = acc[c][r];
    }
    __syncthreads();
    if (kh == 0) {
#pragma unroll
        for (int c = 0; c < 5; c++)
#pragma unroll
            for (int r = 0; r < 4; r++) acc[c][r] += smP[pid * 21 + c * 4 + r];
    }

    if (blockIdx.y != 0) {
        if (kh == 0) {
            const int m0 = mt * 16;
#pragma unroll
            for (int c = 0; c < 5; c++) {
                int col = (nh * 5 + c) * 16 + m15;
#pragma unroll
                for (int r = 0; r < 4; r++) {
                    int row = m0 + (l >> 4) * 4 + r;
                    C[(size_t)row * HPAD + col] = (_Float16)acc[c][r];
                }
            }
        }
        return;
    }

    if (kh == 0) {
#pragma unroll
        for (int c = 0; c < 5; c++) {
            int u   = nh * 5 + c;
            int col = u * 16 + m15;
            float bb = (col < HID) ? ab1[col] : 0.f;
            int kt2 = u >> 1;
            int g  = (u & 1) * 2 + (m15 >> 3);
            int e  = m15 & 7;
#pragma unroll
            for (int r = 0; r < 4; r++) {
                int rloc = (l >> 4) * 4 + r;
                float v = fmaxf(acc[c][r] + bb, 0.f);
                hh[((mtl * 5 + kt2) * 64 + g * 16 + rloc) * 8 + e] = (_Float16)v;
            }
        }
    }
    __syncthreads();

    if (kh == 0) {
        const f16x8* pH = (const f16x8*)hh;
        const f16x8* pB2 = (const f16x8*)fA2;
        f32x4 acc2[5];
#pragma unroll
        for (int c = 0; c < 5; c++) acc2[c] = (f32x4){0.f, 0.f, 0.f, 0.f};
#pragma unroll
        for (int kt = 0; kt < 5; ++kt) {
            f16x8 a = pH[(mtl * 5 + kt) * 64 + l];
#pragma unroll
            for (int c = 0; c < 5; c++) {
                f16x8 bv = pB2[(size_t)(kt * NT + nh * 5 + c) * 64 + l];
                acc2[c] = __builtin_amdgcn_mfma_f32_16x16x32_f16(a, bv, acc2[c], 0, 0, 0);
            }
        }
        float p[4] = {0.f, 0.f, 0.f, 0.f};
#pragma unroll
        for (int c = 0; c < 5; c++) {
            int col = (nh * 5 + c) * 16 + m15;
            float bb = (col < HID) ? ab2[col] : 0.f;
            float wv = (col < HID) ? aW3[col] : 0.f;
#pragma unroll
            for (int r = 0; r < 4; r++) {
                float v = fmaxf(acc2[c][r] + bb, 0.f);
                p[r] = fmaf(v, wv, p[r]);
            }
        }
#pragma unroll
        for (int off = 1; off < 16; off <<= 1)
#pragma unroll
            for (int r = 0; r < 4; r++) p[r] += __shfl_xor(p[r], off);
        if (m15 == 0)
#pragma unroll
            for (int r = 0; r < 4; r++) red[mtl * 2 + nh][(l >> 4) * 4 + r] = p[r];
    }
    __syncthreads();
    if (tid < 32) {
        scores[blockIdx.x * 32 + tid] =
            red[(tid >> 4) * 2 + 0][tid & 15] + red[(tid >> 4) * 2 + 1][tid & 15] + ab3[0];
    }
}

// ---------------- k_spanfinal: 1279 blocks x 32 spans.
// phase0: wave-parallel softmax; E-ONLY LDS staging (13 KB, occupancy-safe);
// phase1: pool (E from LDS when window contiguous); phase2: GEMM -> out
__global__ __launch_bounds__(256) void k_spanfinal(
    const float* __restrict__ scores, const _Float16* __restrict__ Abuf,
    const _Float16* __restrict__ Bbuf, const _Float16* __restrict__ Ebuf,
    const float* __restrict__ wc,
    const _Float16* __restrict__ fW2,
    const float* __restrict__ sb2, const float* __restrict__ sW3,
    const float* __restrict__ sb3, float* __restrict__ out)
{
    __shared__ alignas(16) _Float16 hh[5120];
    __shared__ alignas(16) _Float16 Etile[41 * HPAD];   // 13120 B
    __shared__ float wg[32][10];
    __shared__ int   stI[32], nnI[32];
    __shared__ int   mm[2];
    __shared__ float red[4][16];

    const int tid = threadIdx.x;
    const int s0  = blockIdx.x * 32;

    // phase 0: softmax, 8 lanes per span
    {
        int sl = tid >> 3, k = tid & 7;
        int span = s0 + sl;
        int n = 1, start = 0;
        if (span < NSPAN) {
            int base = 0;
#pragma unroll
            for (int i = 1; i <= MAXW; i++) {
                int ww = T_TOK - i + 1;
                if (span < base + ww) { n = i; break; }
                base += ww;
            }
            start = span - base;
        }
        float x0 = (k < n)     ? scores[start + k]     : -1e30f;
        float x1 = (k + 8 < n) ? scores[start + k + 8] : -1e30f;
        float m = fmaxf(x0, x1);
        m = fmaxf(m, __shfl_xor(m, 1));
        m = fmaxf(m, __shfl_xor(m, 2));
        m = fmaxf(m, __shfl_xor(m, 4));
        float e0 = __expf(x0 - m), e1 = __expf(x1 - m);
        float s = e0 + e1;
        s += __shfl_xor(s, 1);
        s += __shfl_xor(s, 2);
        s += __shfl_xor(s, 4);
        float inv = 1.f / s;
        wg[sl][k] = e0 * inv;
        if (k < 2) wg[sl][k + 8] = e1 * inv;
        if (k == 0) { stI[sl] = start; nnI[sl] = n; }
    }
    __syncthreads();

    if (tid == 0) {
        int lo = stI[0], hi = stI[0] + nnI[0];
#pragma unroll
        for (int i = 1; i < 32; i++) {
            lo = min(lo, stI[i]);
            hi = max(hi, stI[i] + nnI[i]);
        }
        mm[0] = lo; mm[1] = hi;
    }
    __syncthreads();
    const int e0r = mm[0];
    const bool staged = (mm[1] - e0r) <= 41;

    if (staged) {
        // stage E rows e0r..e0r+40 once (820 f16x8 tasks)
        for (int t = tid; t < 820; t += 256) {
            int row = t / 20, q = t - row * 20;
            int gr = min(e0r + row, T_TOK - 1);
            *(f16x8*)(Etile + row * HPAD + q * 8) =
                *(const f16x8*)(Ebuf + (size_t)gr * HPAD + q * 8);
        }
    }
    __syncthreads();

    // phase 1: 640 tasks (32 spans x 20 8-col groups)
#pragma unroll
    for (int it = 0; it < 3; ++it) {
        int task = it * 256 + tid;
        if (task < 640) {
            int sl = task / 20;
            int q  = task - sl * 20;
            int start = stI[sl];
            int nn = nnI[sl];
            int d0 = q * 8;
            f16x8 a8 = *(const f16x8*)(Abuf + (size_t)start * HPAD + d0);
            f16x8 b8 = *(const f16x8*)(Bbuf + (size_t)(start + nn - 1) * HPAD + d0);
            const float* wr = wc + (nn - 1) * HPAD + d0;
            float v[8];
#pragma unroll
            for (int e = 0; e < 8; e++) v[e] = (float)a8[e] + (float)b8[e] + wr[e];
            if (staged) {
#pragma unroll
                for (int i = 0; i < MAXW; i++) {
                    int rr = min(start + i - e0r, 40);
                    f16x8 e8 = *(const f16x8*)(Etile + rr * HPAD + d0);
                    float aa = wg[sl][i];
#pragma unroll
                    for (int e = 0; e < 8; e++) v[e] = fmaf(aa, (float)e8[e], v[e]);
                }
            } else {
#pragma unroll
                for (int i = 0; i < MAXW; i++) {
                    int ridx = min(start + i, T_TOK - 1);
                    f16x8 e8 = *(const f16x8*)(Ebuf + (size_t)ridx * HPAD + d0);
                    float aa = wg[sl][i];
#pragma unroll
                    for (int e = 0; e < 8; e++) v[e] = fmaf(aa, (float)e8[e], v[e]);
                }
            }
            f16x8 hv;
#pragma unroll
            for (int e = 0; e < 8; e++) hv[e] = (_Float16)fmaxf(v[e], 0.f);
            int mtl = sl >> 4, smr = sl & 15;
            int kt = q >> 2, gg = q & 3;
            *(f16x8*)(hh + ((mtl * 5 + kt) * 64 + gg * 16 + smr) * 8) = hv;
        }
    }
    __syncthreads();

    // phase 2: GEMM (K=160) vs fW2 + relu + dot(sW3) -> out
    const int w = tid >> 6, l = tid & 63;
    const int mtl = w >> 1, nh = w & 1;
    const int m15 = l & 15;
    const f16x8* pH = (const f16x8*)hh;
    const f16x8* pB = (const f16x8*)fW2;
    f32x4 acc[5];
#pragma unroll
    for (int c = 0; c < 5; c++) acc[c] = (f32x4){0.f, 0.f, 0.f, 0.f};
#pragma unroll
    for (int kt = 0; kt < 5; ++kt) {
        f16x8 a = pH[(mtl * 5 + kt) * 64 + l];
#pragma unroll
        for (int c = 0; c < 5; c++) {
            f16x8 bv = pB[(size_t)(kt * NT + nh * 5 + c) * 64 + l];
            acc[c] = __builtin_amdgcn_mfma_f32_16x16x32_f16(a, bv, acc[c], 0, 0, 0);
        }
    }
    float p[4] = {0.f, 0.f, 0.f, 0.f};
#pragma unroll
    for (int c = 0; c < 5; c++) {
        int col = (nh * 5 + c) * 16 + m15;
        float bb = (col < HID) ? sb2[col] : 0.f;
        float wv = (col < HID) ? sW3[col] : 0.f;
#pragma unroll
        for (int r = 0; r < 4; r++) {
            float v = fmaxf(acc[c][r] + bb, 0.f);
            p[r] = fmaf(v, wv, p[r]);
        }
    }
#pragma unroll
    for (int off = 1; off < 16; off <<= 1)
#pragma unroll
        for (int r = 0; r < 4; r++) p[r] += __shfl_xor(p[r], off);
    if (m15 == 0)
#pragma unroll
        for (int r = 0; r < 4; r++) red[w][(l >> 4) * 4 + r] = p[r];
    __syncthreads();
    if (tid < 32) {
        int row = s0 + tid;
        if (row < NSPAN)
            out[row] = red[(tid >> 4) * 2 + 0][tid & 15] +
                       red[(tid >> 4) * 2 + 1][tid & 15] + sb3[0];
    }
}

extern "C" void kernel_launch(void* const* d_in, const int* in_sizes, int n_in,
                              void* d_out, int out_size, void* d_ws, size_t ws_size,
                              hipStream_t stream) {
    const float* embeds = (const float*)d_in[0];
    const float* states = (const float*)d_in[1];
    const float* aW1 = (const float*)d_in[2];
    const float* ab1 = (const float*)d_in[3];
    const float* aW2 = (const float*)d_in[4];
    const float* ab2 = (const float*)d_in[5];
    const float* aW3 = (const float*)d_in[6];
    const float* ab3 = (const float*)d_in[7];
    const float* wt  = (const float*)d_in[8];
    const float* sW1 = (const float*)d_in[9];
    const float* sb1 = (const float*)d_in[10];
    const float* sW2 = (const float*)d_in[11];
    const float* sb2 = (const float*)d_in[12];
    const float* sW3 = (const float*)d_in[13];
    const float* sb3 = (const float*)d_in[14];
    float* out = (float*)d_out;

    char* W = (char*)d_ws;
    _Float16* Abuf = (_Float16*)(W + 0);          // 4096*160*2 = 1310720
    _Float16* Bbuf = (_Float16*)(W + 1310720);
    _Float16* Ebuf = (_Float16*)(W + 2621440);
    float* scores  = (float*)(W + 3932160);       // 16384
    float* wcbuf   = (float*)(W + 3948544);       // 6400
    _Float16* fW1  = (_Float16*)(W + 3954944);    // 416*160*2 = 133120
    _Float16* fA1  = (_Float16*)(W + 4088064);
    _Float16* fB1  = (_Float16*)(W + 4221184);
    _Float16* fE1  = (_Float16*)(W + 4354304);    // 320*160*2 = 102400
    _Float16* fA2  = (_Float16*)(W + 4456704);    // 160*160*2 = 51200
    _Float16* fW2  = (_Float16*)(W + 4507904);

    // weight frags + width constants (158 blocks)
    k_prep<<<158, 256, 0, stream>>>(aW1, sW1, aW2, sW2, wt, sb1,
                                    fW1, fA1, fB1, fE1, fA2, fW2, wcbuf);
    // projections + fused attention -> scores (512 blocks x 8 waves, split-K)
    k_proj<<<dim3(128, 4), 512, 0, stream>>>(states, embeds,
        fW1, fA1, fB1, fE1, fA2, ab1, ab2, aW3, ab3, Abuf, Bbuf, Ebuf, scores);
    // spans + final MLP -> out (1279 blocks, E-only LDS staging)
    k_spanfinal<<<1279, 256, 0, stream>>>(scores, Abuf, Bbuf, Ebuf, wcbuf,
        fW2, sb2, sW3, sb3, out);
}

// Round 16
// 37.557 us; speedup vs baseline: 2.0808x; 1.0396x over previous
//
#include <hip/hip_runtime.h>
#include <hip/hip_bf16.h>

#define T_TOK 4096
#define HID   150
#define HPAD  160
#define NSPAN 40915
#define MAXW  10
#define NT    10             // 160/16 col tiles

typedef __attribute__((ext_vector_type(8))) _Float16 f16x8;
typedef __attribute__((ext_vector_type(4))) float    f32x4;

static __device__ __forceinline__ f16x8 cvt8(const float* __restrict__ row, int kbase, int K) {
    f16x8 a;
    if (kbase + 8 <= K) {
        float4 v0 = *(const float4*)(row + kbase);
        float4 v1 = *(const float4*)(row + kbase + 4);
        a[0] = (_Float16)v0.x; a[1] = (_Float16)v0.y;
        a[2] = (_Float16)v0.z; a[3] = (_Float16)v0.w;
        a[4] = (_Float16)v1.x; a[5] = (_Float16)v1.y;
        a[6] = (_Float16)v1.z; a[7] = (_Float16)v1.w;
    } else {
#pragma unroll
        for (int e = 0; e < 8; e++)
            a[e] = (_Float16)((kbase + e < K) ? row[kbase + e] : 0.f);
    }
    return a;
}

// ---------------- k_prep: weight frag conversions + width constants (158 blocks)
__global__ __launch_bounds__(256) void k_prep(
    const float* __restrict__ aW1, const float* __restrict__ sW1,
    const float* __restrict__ aW2, const float* __restrict__ sW2,
    const float* __restrict__ wt, const float* __restrict__ sb1,
    _Float16* __restrict__ fW1, _Float16* __restrict__ fA1,
    _Float16* __restrict__ fB1, _Float16* __restrict__ fE1,
    _Float16* __restrict__ fA2, _Float16* __restrict__ fW2,
    float* __restrict__ wc)
{
    const int b = blockIdx.x;
    const int w = threadIdx.x >> 6, l = threadIdx.x & 63;

    if (b < 148) {
        int tw = b * 4 + w;
        if (tw >= 590) return;
        const float* src; int srcK, off; _Float16* d;
        if      (tw < 130) { src = aW1;             srcK = 400; off = 0;   d = fW1; }
        else if (tw < 260) { src = sW1;             srcK = 400; off = 130; d = fA1; }
        else if (tw < 390) { src = sW1 + 400 * HID; srcK = 400; off = 260; d = fB1; }
        else if (tw < 490) { src = sW1 + 800 * HID; srcK = 300; off = 390; d = fE1; }
        else if (tw < 540) { src = aW2;             srcK = 150; off = 490; d = fA2; }
        else               { src = sW2;             srcK = 150; off = 540; d = fW2; }
        int tb = tw - off;
        int kt = tb / NT, nt = tb - kt * NT;
        int n = nt * 16 + (l & 15);
        int kbase = kt * 32 + (l >> 4) * 8;
        f16x8 hv;
#pragma unroll
        for (int e = 0; e < 8; e++) {
            int k = kbase + e;
            float f = (k < srcK && n < HID) ? src[(size_t)k * HID + n] : 0.f;
            hv[e] = (_Float16)f;
        }
        *(f16x8*)(d + ((size_t)tb * 64 + l) * 8) = hv;
    } else {
        int n = b - 147;             // 1..10
        int c = threadIdx.x;
        if (c >= HPAD) return;
        float s = 0.f;
        if (c < HID) {
            const int dt[11] = {0, 1, 2, 3, 4, 4, 4, 4, 5, 5, 5};
            const float* ww = wt + dt[n] * 20;
            s = sb1[c];
#pragma unroll
            for (int j = 0; j < 20; j++) s = fmaf(ww[j], sW1[(1100 + j) * HID + c], s);
        }
        wc[(n - 1) * HPAD + c] = s;
    }
}

// ---------------- k_proj: grid (128, 4) x 512 threads (8 waves), split-K.
__global__ __launch_bounds__(512) void k_proj(
    const float* __restrict__ states, const float* __restrict__ embeds,
    const _Float16* __restrict__ fW1, const _Float16* __restrict__ fA1,
    const _Float16* __restrict__ fB1, const _Float16* __restrict__ fE1,
    const _Float16* __restrict__ fA2,
    const float* __restrict__ ab1, const float* __restrict__ ab2,
    const float* __restrict__ aW3, const float* __restrict__ ab3,
    _Float16* __restrict__ Abuf, _Float16* __restrict__ Bbuf,
    _Float16* __restrict__ Ebuf, float* __restrict__ scores)
{
    __shared__ float smP[256 * 21];
    __shared__ alignas(16) _Float16 hh[5120];
    __shared__ float red[4][16];

    const float* Asrc; int lda, srcK, KT; const _Float16* Bf; _Float16* C = nullptr;
    switch (blockIdx.y) {
        case 0: Asrc = states; lda = 400; srcK = 400; KT = 13; Bf = fW1; break;
        case 1: Asrc = states; lda = 400; srcK = 400; KT = 13; Bf = fA1; C = Abuf; break;
        case 2: Asrc = states; lda = 400; srcK = 400; KT = 13; Bf = fB1; C = Bbuf; break;
        default:Asrc = embeds; lda = 300; srcK = 300; KT = 10; Bf = fE1; C = Ebuf; break;
    }
    const int tid = threadIdx.x;
    const int w   = tid >> 6, l = tid & 63;
    const int mtl = w >> 2;
    const int nh  = (w >> 1) & 1;
    const int kh  = w & 1;
    const int mt  = blockIdx.x * 2 + mtl;
    const int m15 = l & 15;
    const int koff = (l >> 4) * 8;
    const float* arow = Asrc + (size_t)(mt * 16 + m15) * lda;
    const f16x8* pB = (const f16x8*)Bf;
    const int pid = (mtl * 2 + nh) * 64 + l;

    f32x4 acc[5];
#pragma unroll
    for (int c = 0; c < 5; c++) acc[c] = (f32x4){0.f, 0.f, 0.f, 0.f};

    if (KT == 13) {
        if (kh == 0) {
#pragma unroll
            for (int kt = 0; kt < 7; ++kt) {
                f16x8 a = cvt8(arow, kt * 32 + koff, 400);
#pragma unroll
                for (int c = 0; c < 5; c++) {
                    f16x8 bv = pB[(size_t)(kt * NT + nh * 5 + c) * 64 + l];
                    acc[c] = __builtin_amdgcn_mfma_f32_16x16x32_f16(a, bv, acc[c], 0, 0, 0);
                }
            }
        } else {
#pragma unroll
            for (int kt = 7; kt < 13; ++kt) {
                f16x8 a = cvt8(arow, kt * 32 + koff, 400);
#pragma unroll
                for (int c = 0; c < 5; c++) {
                    f16x8 bv = pB[(size_t)(kt * NT + nh * 5 + c) * 64 + l];
                    acc[c] = __builtin_amdgcn_mfma_f32_16x16x32_f16(a, bv, acc[c], 0, 0, 0);
                }
            }
        }
    } else {
        if (kh == 0) {
#pragma unroll
            for (int kt = 0; kt < 5; ++kt) {
                f16x8 a = cvt8(arow, kt * 32 + koff, 300);
#pragma unroll
                for (int c = 0; c < 5; c++) {
                    f16x8 bv = pB[(size_t)(kt * NT + nh * 5 + c) * 64 + l];
                    acc[c] = __builtin_amdgcn_mfma_f32_16x16x32_f16(a, bv, acc[c], 0, 0, 0);
                }
            }
        } else {
#pragma unroll
            for (int kt = 5; kt < 10; ++kt) {
                f16x8 a = cvt8(arow, kt * 32 + koff, 300);
#pragma unroll
                for (int c = 0; c < 5; c++) {
                    f16x8 bv = pB[(size_t)(kt * NT + nh * 5 + c) * 64 + l];
                    acc[c] = __builtin_amdgcn_mfma_f32_16x16x32_f16(a, bv, acc[c], 0, 0, 0);
                }
            }
        }
    }

    if (kh == 1) {
#pragma unroll
        for (int c = 0; c < 5; c++)
#pragma unroll
            for (int r = 0; r < 4; r++) smP[pid * 21 + c * 4 + r] = acc[c][r];
    }
    __syncthreads();
    if (kh == 0) {
#pragma unroll
        for (int c = 0; c < 5; c++)
#pragma unroll
            for (int r = 0; r < 4; r++) acc[c][r] += smP[pid * 21 + c * 4 + r];
    }

    if (blockIdx.y != 0) {
        if (kh == 0) {
            const int m0 = mt * 16;
#pragma unroll
            for (int c = 0; c < 5; c++) {
                int col = (nh * 5 + c) * 16 + m15;
#pragma unroll
                for (int r = 0; r < 4; r++) {
                    int row = m0 + (l >> 4) * 4 + r;
                    C[(size_t)row * HPAD + col] = (_Float16)acc[c][r];
                }
            }
        }
        return;
    }

    if (kh == 0) {
#pragma unroll
        for (int c = 0; c < 5; c++) {
            int u   = nh * 5 + c;
            int col = u * 16 + m15;
            float bb = (col < HID) ? ab1[col] : 0.f;
            int kt2 = u >> 1;
            int g  = (u & 1) * 2 + (m15 >> 3);
            int e  = m15 & 7;
#pragma unroll
            for (int r = 0; r < 4; r++) {
                int rloc = (l >> 4) * 4 + r;
                float v = fmaxf(acc[c][r] + bb, 0.f);
                hh[((mtl * 5 + kt2) * 64 + g * 16 + rloc) * 8 + e] = (_Float16)v;
            }
        }
    }
    __syncthreads();

    if (kh == 0) {
        const f16x8* pH = (const f16x8*)hh;
        const f16x8* pB2 = (const f16x8*)fA2;
        f32x4 acc2[5];
#pragma unroll
        for (int c = 0; c < 5; c++) acc2[c] = (f32x4){0.f, 0.f, 0.f, 0.f};
#pragma unroll
        for (int kt = 0; kt < 5; ++kt) {
            f16x8 a = pH[(mtl * 5 + kt) * 64 + l];
#pragma unroll
            for (int c = 0; c < 5; c++) {
                f16x8 bv = pB2[(size_t)(kt * NT + nh * 5 + c) * 64 + l];
                acc2[c] = __builtin_amdgcn_mfma_f32_16x16x32_f16(a, bv, acc2[c], 0, 0, 0);
            }
        }
        float p[4] = {0.f, 0.f, 0.f, 0.f};
#pragma unroll
        for (int c = 0; c < 5; c++) {
            int col = (nh * 5 + c) * 16 + m15;
            float bb = (col < HID) ? ab2[col] : 0.f;
            float wv = (col < HID) ? aW3[col] : 0.f;
#pragma unroll
            for (int r = 0; r < 4; r++) {
                float v = fmaxf(acc2[c][r] + bb, 0.f);
                p[r] = fmaf(v, wv, p[r]);
            }
        }
#pragma unroll
        for (int off = 1; off < 16; off <<= 1)
#pragma unroll
            for (int r = 0; r < 4; r++) p[r] += __shfl_xor(p[r], off);
        if (m15 == 0)
#pragma unroll
            for (int r = 0; r < 4; r++) red[mtl * 2 + nh][(l >> 4) * 4 + r] = p[r];
    }
    __syncthreads();
    if (tid < 32) {
        scores[blockIdx.x * 32 + tid] =
            red[(tid >> 4) * 2 + 0][tid & 15] + red[(tid >> 4) * 2 + 1][tid & 15] + ab3[0];
    }
}

// ---------------- k_spanfinal: 1279 blocks x 32 spans.
__global__ __launch_bounds__(256) void k_spanfinal(
    const float* __restrict__ scores, const _Float16* __restrict__ Abuf,
    const _Float16* __restrict__ Bbuf, const _Float16* __restrict__ Ebuf,
    const float* __restrict__ wc,
    const _Float16* __restrict__ fW2,
    const float* __restrict__ sb2, const float* __restrict__ sW3,
    const float* __restrict__ sb3, float* __restrict__ out)
{
    __shared__ alignas(16) _Float16 hh[5120];
    __shared__ float wg[32][10];
    __shared__ int   stI[32], nnI[32];
    __shared__ float red[4][16];

    const int tid = threadIdx.x;
    const int s0  = blockIdx.x * 32;

    // phase 0: softmax, 8 lanes per span
    {
        int sl = tid >> 3, k = tid & 7;
        int span = s0 + sl;
        int n = 1, start = 0;
        if (span < NSPAN) {
            int base = 0;
#pragma unroll
            for (int i = 1; i <= MAXW; i++) {
                int ww = T_TOK - i + 1;
                if (span < base + ww) { n = i; break; }
                base += ww;
            }
            start = span - base;
        }
        float x0 = (k < n)     ? scores[start + k]     : -1e30f;
        float x1 = (k + 8 < n) ? scores[start + k + 8] : -1e30f;
        float m = fmaxf(x0, x1);
        m = fmaxf(m, __shfl_xor(m, 1));
        m = fmaxf(m, __shfl_xor(m, 2));
        m = fmaxf(m, __shfl_xor(m, 4));
        float e0 = __expf(x0 - m), e1 = __expf(x1 - m);
        float s = e0 + e1;
        s += __shfl_xor(s, 1);
        s += __shfl_xor(s, 2);
        s += __shfl_xor(s, 4);
        float inv = 1.f / s;
        wg[sl][k] = e0 * inv;
        if (k < 2) wg[sl][k + 8] = e1 * inv;
        if (k == 0) { stI[sl] = start; nnI[sl] = n; }
    }
    __syncthreads();

    // phase 1: 640 tasks
#pragma unroll
    for (int it = 0; it < 3; ++it) {
        int task = it * 256 + tid;
        if (task < 640) {
            int sl = task / 20;
            int q  = task - sl * 20;
            int start = stI[sl];
            int nn = nnI[sl];
            int d0 = q * 8;
            f16x8 a8 = *(const f16x8*)(Abuf + (size_t)start * HPAD + d0);
            f16x8 b8 = *(const f16x8*)(Bbuf + (size_t)(start + nn - 1) * HPAD + d0);
            const float* wr = wc + (nn - 1) * HPAD + d0;
            float v[8];
#pragma unroll
            for (int e = 0; e < 8; e++) v[e] = (float)a8[e] + (float)b8[e] + wr[e];
#pragma unroll
            for (int i = 0; i < MAXW; i++) {
                int ridx = min(start + i, T_TOK - 1);
                f16x8 e8 = *(const f16x8*)(Ebuf + (size_t)ridx * HPAD + d0);
                float aa = wg[sl][i];
#pragma unroll
                for (int e = 0; e < 8; e++) v[e] = fmaf(aa, (float)e8[e], v[e]);
            }
            f16x8 hv;
#pragma unroll
            for (int e = 0; e < 8; e++) hv[e] = (_Float16)fmaxf(v[e], 0.f);
            int mtl = sl >> 4, smr = sl & 15;
            int kt = q >> 2, gg = q & 3;
            *(f16x8*)(hh + ((mtl * 5 + kt) * 64 + gg * 16 + smr) * 8) = hv;
        }
    }
    __syncthreads();

    // phase 2: GEMM (K=160) vs fW2 + relu + dot(sW3) -> out
    const int w = tid >> 6, l = tid & 63;
    const int mtl = w >> 1, nh = w & 1;
    const int m15 = l & 15;
    const f16x8* pH = (const f16x8*)hh;
    const f16x8* pB = (const f16x8*)fW2;
    f32x4 acc[5];
#pragma unroll
    for (int c = 0; c < 5; c++) acc[c] = (f32x4){0.f, 0.f, 0.f, 0.f};
#pragma unroll
    for (int kt = 0; kt < 5; ++kt) {
        f16x8 a = pH[(mtl * 5 + kt) * 64 + l];
#pragma unroll
        for (int c = 0; c < 5; c++) {
            f16x8 bv = pB[(size_t)(kt * NT + nh * 5 + c) * 64 + l];
            acc[c] = __builtin_amdgcn_mfma_f32_16x16x32_f16(a, bv, acc[c], 0, 0, 0);
        }
    }
    float p[4] = {0.f, 0.f, 0.f, 0.f};
#pragma unroll
    for (int c = 0; c < 5; c++) {
        int col = (nh * 5 + c) * 16 + m15;
        float bb = (col < HID) ? sb2[col] : 0.f;
        float wv = (col < HID) ? sW3[col] : 0.f;
#pragma unroll
        for (int r = 0; r < 4; r++) {
            float v = fmaxf(acc[c][r] + bb, 0.f);
            p[r] = fmaf(v, wv, p[r]);
        }
    }
#pragma unroll
    for (int off = 1; off < 16; off <<= 1)
#pragma unroll
        for (int r = 0; r < 4; r++) p[r] += __shfl_xor(p[r], off);
    if (m15 == 0)
#pragma unroll
        for (int r = 0; r < 4; r++) red[w][(l >> 4) * 4 + r] = p[r];
    __syncthreads();
    if (tid < 32) {
        int row = s0 + tid;
        if (row < NSPAN)
            out[row] = red[(tid >> 4) * 2 + 0][tid & 15] +
                       red[(tid >> 4) * 2 + 1][tid & 15] + sb3[0];
    }
}

extern "C" void kernel_launch(void* const* d_in, const int* in_sizes, int n_in,
                              void* d_out, int out_size, void* d_ws, size_t ws_size,
                              hipStream_t stream) {
    const float* embeds = (const float*)d_in[0];
    const float* states = (const float*)d_in[1];
    const float* aW1 = (const float*)d_in[2];
    const float* ab1 = (const float*)d_in[3];
    const float* aW2 = (const float*)d_in[4];
    const float* ab2 = (const float*)d_in[5];
    const float* aW3 = (const float*)d_in[6];
    const float* ab3 = (const float*)d_in[7];
    const float* wt  = (const float*)d_in[8];
    const float* sW1 = (const float*)d_in[9];
    const float* sb1 = (const float*)d_in[10];
    const float* sW2 = (const float*)d_in[11];
    const float* sb2 = (const float*)d_in[12];
    const float* sW3 = (const float*)d_in[13];
    const float* sb3 = (const float*)d_in[14];
    float* out = (float*)d_out;

    char* W = (char*)d_ws;
    _Float16* Abuf = (_Float16*)(W + 0);          // 4096*160*2 = 1310720
    _Float16* Bbuf = (_Float16*)(W + 1310720);
    _Float16* Ebuf = (_Float16*)(W + 2621440);
    float* scores  = (float*)(W + 3932160);       // 16384
    float* wcbuf   = (float*)(W + 3948544);       // 6400
    _Float16* fW1  = (_Float16*)(W + 3954944);    // 416*160*2 = 133120
    _Float16* fA1  = (_Float16*)(W + 4088064);
    _Float16* fB1  = (_Float16*)(W + 4221184);
    _Float16* fE1  = (_Float16*)(W + 4354304);    // 320*160*2 = 102400
    _Float16* fA2  = (_Float16*)(W + 4456704);    // 160*160*2 = 51200
    _Float16* fW2  = (_Float16*)(W + 4507904);

    // weight frags + width constants (158 blocks)
    k_prep<<<158, 256, 0, stream>>>(aW1, sW1, aW2, sW2, wt, sb1,
                                    fW1, fA1, fB1, fE1, fA2, fW2, wcbuf);
    // projections + fused attention -> scores (512 blocks x 8 waves, split-K)
    k_proj<<<dim3(128, 4), 512, 0, stream>>>(states, embeds,
        fW1, fA1, fB1, fE1, fA2, ab1, ab2, aW3, ab3, Abuf, Bbuf, Ebuf, scores);
    // spans + final MLP -> out (1279 blocks)
    k_spanfinal<<<1279, 256, 0, stream>>>(scores, Abuf, Bbuf, Ebuf, wcbuf,
        fW2, sb2, sW3, sb3, out);
}